// Round 4
// baseline (601.932 us; speedup 1.0000x reference)
//
#include <hip/hip_runtime.h>
#include <stdint.h>

#define NN   8192
#define FIN  128
#define DM   256
#define DI   512
#define DST  16
#define NC   256   // scan chunks
#define CL   32    // chunk length

typedef short bf16x8 __attribute__((ext_vector_type(8)));
typedef float f32x4 __attribute__((ext_vector_type(4)));
union FragU { unsigned u[4]; uint4 u4; bf16x8 v; };

__device__ __forceinline__ unsigned short f2bf(float x){
  unsigned u = __float_as_uint(x);
  return (unsigned short)((u + 0x7FFFu + ((u >> 16) & 1u)) >> 16);
}
__device__ __forceinline__ unsigned pack2(float a, float b){
  return (unsigned)f2bf(a) | ((unsigned)f2bf(b) << 16);
}
// fast round-to-nearest pack (one v_perm for hi16 of both)
__device__ __forceinline__ unsigned pack2rn(float a, float b){
  unsigned ua = __float_as_uint(a) + 0x8000u;
  unsigned ub = __float_as_uint(b) + 0x8000u;
  return __builtin_amdgcn_perm(ub, ua, 0x07060302u);
}
__device__ __forceinline__ float bf2f(unsigned short u){
  return __uint_as_float(((unsigned)u) << 16);
}
__device__ __forceinline__ float sigmoidf_(float x){ return 1.f / (1.f + __expf(-x)); }
__device__ __forceinline__ f32x4 zero4(){ f32x4 z; z[0]=0.f; z[1]=0.f; z[2]=0.f; z[3]=0.f; return z; }

#define ASYNC16(g, l) __builtin_amdgcn_global_load_lds( \
    (const __attribute__((address_space(1))) void*)(g), \
    (__attribute__((address_space(3))) void*)(l), 16, 0, 0)
#define WAITVM10 asm volatile("s_waitcnt vmcnt(10)" ::: "memory")
#define WAITVM0  asm volatile("s_waitcnt vmcnt(0)" ::: "memory")
#define WAITLGKM0 asm volatile("s_waitcnt lgkmcnt(0)" ::: "memory")
#define BARRIER  asm volatile("s_barrier" ::: "memory")

// ---------------- workspace layout ----------------
constexpr size_t OFF_XWT   = 0;                                  // xw^T bf16 [256][8192]
constexpr size_t OFF_HB    = OFF_XWT   + (size_t)DM*NN*2;        // relu(h) bf16
constexpr size_t OFF_HBNB  = OFF_HB    + (size_t)NN*DM*2;        // BN'd h bf16
constexpr size_t OFF_WINB  = OFF_HBNB  + (size_t)NN*DM*2;        // w_in bf16 [1024][256]
constexpr size_t OFF_WXPB  = OFF_WINB  + (size_t)1024*256*2;     // w_xproj bf16 [48][512]
constexpr size_t OFF_WOUTB = OFF_WXPB  + (size_t)48*512*2;       // w_out bf16 [256][512]
constexpr size_t OFF_XMB   = OFF_WOUTB + (size_t)256*512*2;      // xm bf16 [8192][512]
constexpr size_t OFF_ZB    = OFF_XMB   + (size_t)NN*DI*2;        // z bf16 [8192][512]
constexpr size_t OFF_XCB   = OFF_ZB    + (size_t)NN*DI*2;        // xc bf16
constexpr size_t OFF_XDBL  = OFF_XCB   + (size_t)NN*DI*2;        // x_dbl fp32 [8192][48]
constexpr size_t OFF_DT    = OFF_XDBL  + (size_t)NN*48*4;        // dt fp32 [8192][512]
constexpr size_t OFF_PF    = OFF_DT    + (size_t)NN*DI*4;        // chunk {P,F} float2 [256][8192]
constexpr size_t OFF_CY    = OFF_PF    + (size_t)NC*DI*DST*8;    // carry fp32 [256][8192]
constexpr size_t OFF_YB    = OFF_CY    + (size_t)NC*DI*DST*4;    // gated y bf16
constexpr size_t OFF_BNS   = OFF_YB    + (size_t)NN*DI*2;
constexpr size_t OFF_BNS2  = OFF_BNS   + 256*4;
constexpr size_t WS_NEED   = OFF_BNS2  + 256*4;
// gemm2 fp32 partials [4][8192][256] = 32MB alias onto PF+CY (dead until scanA)
constexpr size_t OFF_HP    = OFF_PF;

// ---------------- prep: fp32 -> bf16 weights ----------------
__global__ __launch_bounds__(256) void prep_kernel(
    const float* __restrict__ w_in, const float* __restrict__ w_xp, const float* __restrict__ w_out,
    unsigned short* __restrict__ o_in, unsigned short* __restrict__ o_xp, unsigned short* __restrict__ o_out)
{
  int i = blockIdx.x * 256 + threadIdx.x;
  if (i < 1024*256) o_in[i]  = f2bf(w_in[i]);
  if (i < 48*512)   o_xp[i]  = f2bf(w_xp[i]);
  if (i < 256*512)  o_out[i] = f2bf(w_out[i]);
}

// ---------------- gemm1: xw = x @ w_gcn, stored transposed bf16 [256][8192] ----------------
__global__ __launch_bounds__(256) void gemm1_kernel(
    const float* __restrict__ x, const float* __restrict__ w, unsigned short* __restrict__ xwT)
{
  __shared__ float xs[16*128];
  const int t = threadIdx.x;
  const int m0 = blockIdx.x * 16;
  {
    int r = t >> 4, c0 = (t & 15) * 8;
    const float* src = x + (size_t)(m0 + r)*FIN + c0;
    *(float4*)&xs[r*128 + c0]     = *(const float4*)src;
    *(float4*)&xs[r*128 + c0 + 4] = *(const float4*)(src + 4);
  }
  __syncthreads();
  const int n = t;
  float acc[16];
  #pragma unroll
  for (int m = 0; m < 16; ++m) acc[m] = 0.f;
  for (int k = 0; k < 128; k += 4){
    float w0 = w[(size_t)k*DM + n];
    float w1 = w[(size_t)(k+1)*DM + n];
    float w2 = w[(size_t)(k+2)*DM + n];
    float w3 = w[(size_t)(k+3)*DM + n];
    #pragma unroll
    for (int m = 0; m < 16; ++m){
      float4 xv = *(const float4*)&xs[m*128 + k];
      acc[m] = fmaf(xv.x, w0, acc[m]);
      acc[m] = fmaf(xv.y, w1, acc[m]);
      acc[m] = fmaf(xv.z, w2, acc[m]);
      acc[m] = fmaf(xv.w, w3, acc[m]);
    }
  }
  unsigned outp[8];
  #pragma unroll
  for (int m = 0; m < 8; ++m) outp[m] = pack2(acc[2*m], acc[2*m+1]);
  unsigned short* dst = xwT + (size_t)n*NN + m0;
  ((uint4*)dst)[0] = *(uint4*)&outp[0];
  ((uint4*)dst)[1] = *(uint4*)&outp[4];
}

// ---------------- gemm2: hp[ks] = adj[:, ks-quarter] @ xw[ks-quarter, :] ----------------
// M-tile 32, N full 256, BK=64, K-split 4. 4 waves (32x64 wave-tiles), 2 blocks/CU,
// depth-2 DMA pipeline (2 x 40KB LDS sets). mult-3 slot swizzle -> conflict-free
// ds_read_b128. vmcnt(10) keeps one full set in flight across barriers.
__global__ __launch_bounds__(256, 2) void gemm2_kernel(
    const float* __restrict__ adj, const unsigned short* __restrict__ xwT,
    float* __restrict__ hp)
{
  extern __shared__ char lds[];   // 2 sets x 40960: A fp32 [32][64] @0 (8KB), B bf16 [256][64] @8192 (32KB)
  const int t = threadIdx.x;
  const int wave = t >> 6, lane = t & 63, r = lane & 15, q = lane >> 4;
  const int mt = (int)blockIdx.x >> 2, ks = (int)blockIdx.x & 3;
  const int m0 = mt * 32;
  const int kb = ks * 2048;

  // A DMA: 2 loads/thread/set. slot si = row*16+d holds src k-group g=(d-3*row)&15
  const float* asrc[2];
  #pragma unroll
  for (int j = 0; j < 2; ++j){
    int si = t + 256*j;
    int row = si >> 4, d = si & 15;
    int g = (d - 3*row) & 15;
    asrc[j] = adj + (size_t)(m0 + row)*NN + kb + g*4;
  }
  // B DMA: 8 loads/thread/set. slot si = n*8+d holds src k-group g=(d-3*n)&7
  const unsigned short* bsrc[8];
  #pragma unroll
  for (int j = 0; j < 8; ++j){
    int si = t + 256*j;
    int n = si >> 3, d = si & 7;
    int g = (d - 3*n) & 7;
    bsrc[j] = xwT + (size_t)n*NN + kb + g*8;
  }

  f32x4 acc[2][4];
  #pragma unroll
  for (int mi = 0; mi < 2; ++mi)
    #pragma unroll
    for (int ni = 0; ni < 4; ++ni) acc[mi][ni] = zero4();

  // prologue: sets 0,1 (20 loads/thread outstanding)
  #pragma unroll
  for (int s = 0; s < 2; ++s){
    char* L = lds + s*40960;
    int k0 = s*64;
    ASYNC16(asrc[0] + k0, L + t*16);
    ASYNC16(asrc[1] + k0, L + (t + 256)*16);
    #pragma unroll
    for (int j = 0; j < 8; ++j)
      ASYNC16(bsrc[j] + k0, L + 8192 + (t + 256*j)*16);
  }

  // fragment LDS offsets
  int aoffF[2][2][2];   // float index: [ks2][mi][pair]
  int boffU[2][4];      // uint4 index: [ks2][ni]
  #pragma unroll
  for (int ks2 = 0; ks2 < 2; ++ks2){
    #pragma unroll
    for (int mi = 0; mi < 2; ++mi){
      int m = mi*16 + r;
      int g0 = ks2*8 + 2*q;
      aoffF[ks2][mi][0] = m*64 + (((g0    ) + 3*m) & 15)*4;
      aoffF[ks2][mi][1] = m*64 + (((g0 + 1) + 3*m) & 15)*4;
    }
    #pragma unroll
    for (int ni = 0; ni < 4; ++ni){
      int n = wave*64 + ni*16 + r;
      int g = ks2*4 + q;
      boffU[ks2][ni] = 512 + n*8 + ((g + 3*n) & 7);
    }
  }

  for (int k = 0; k < 32; ++k){
    if (k < 31) { WAITVM10; } else { WAITVM0; }
    BARRIER;
    char* Lb = lds + (k & 1)*40960;
    const float* Af = (const float*)Lb;
    const uint4* Bu = (const uint4*)Lb;
    float4 pa[2][2][2];
    FragU fb[2][4];
    #pragma unroll
    for (int ks2 = 0; ks2 < 2; ++ks2){
      #pragma unroll
      for (int mi = 0; mi < 2; ++mi){
        pa[ks2][mi][0] = *(const float4*)(Af + aoffF[ks2][mi][0]);
        pa[ks2][mi][1] = *(const float4*)(Af + aoffF[ks2][mi][1]);
      }
      #pragma unroll
      for (int ni = 0; ni < 4; ++ni) fb[ks2][ni].u4 = Bu[boffU[ks2][ni]];
    }
    WAITLGKM0;
    BARRIER;
    if (k < 30){
      int k0 = (k + 2) * 64;
      ASYNC16(asrc[0] + k0, Lb + t*16);
      ASYNC16(asrc[1] + k0, Lb + (t + 256)*16);
      #pragma unroll
      for (int j = 0; j < 8; ++j)
        ASYNC16(bsrc[j] + k0, Lb + 8192 + (t + 256*j)*16);
    }
    FragU fa[2][2];
    #pragma unroll
    for (int ks2 = 0; ks2 < 2; ++ks2)
      #pragma unroll
      for (int mi = 0; mi < 2; ++mi){
        fa[ks2][mi].u[0] = pack2rn(pa[ks2][mi][0].x, pa[ks2][mi][0].y);
        fa[ks2][mi].u[1] = pack2rn(pa[ks2][mi][0].z, pa[ks2][mi][0].w);
        fa[ks2][mi].u[2] = pack2rn(pa[ks2][mi][1].x, pa[ks2][mi][1].y);
        fa[ks2][mi].u[3] = pack2rn(pa[ks2][mi][1].z, pa[ks2][mi][1].w);
      }
    #pragma unroll
    for (int ks2 = 0; ks2 < 2; ++ks2)
      #pragma unroll
      for (int mi = 0; mi < 2; ++mi)
        #pragma unroll
        for (int ni = 0; ni < 4; ++ni)
          acc[mi][ni] = __builtin_amdgcn_mfma_f32_16x16x32_bf16(fa[ks2][mi].v, fb[ks2][ni].v, acc[mi][ni], 0, 0, 0);
  }

  float* hpo = hp + (size_t)ks * ((size_t)NN * DM);
  #pragma unroll
  for (int mi = 0; mi < 2; ++mi)
    #pragma unroll
    for (int ni = 0; ni < 4; ++ni){
      const int n = wave*64 + ni*16 + r;
      #pragma unroll
      for (int jr = 0; jr < 4; ++jr){
        const int m = m0 + mi*16 + q*4 + jr;
        hpo[(size_t)m*DM + n] = acc[mi][ni][jr];
      }
    }
}

// ---------------- hred: h = relu(sum of 4 partials + bias) -> bf16, + BN stats ----------------
__global__ __launch_bounds__(256) void hred_kernel(
    const float* __restrict__ hp, const float* __restrict__ b_gcn,
    unsigned short* __restrict__ hb, float* __restrict__ bns, float* __restrict__ bns2)
{
  const size_t NND = (size_t)NN * DM;
  const int c = threadIdx.x;
  const int m0 = blockIdx.x * 32;
  const float bias = b_gcn[c];
  float s1 = 0.f, s2 = 0.f;
  #pragma unroll 8
  for (int rr = 0; rr < 32; ++rr){
    size_t idx = (size_t)(m0 + rr)*DM + c;
    float v = hp[idx] + hp[NND + idx] + hp[2*NND + idx] + hp[3*NND + idx] + bias;
    v = fmaxf(v, 0.f);
    hb[idx] = f2bf(v);
    s1 += v; s2 += v*v;
  }
  atomicAdd(bns + c, s1);
  atomicAdd(bns2 + c, s2);
}

// ---------------- bnapply: hbnb = BN(hb) bf16 ----------------
__global__ __launch_bounds__(256) void bnapply_kernel(
    const unsigned short* __restrict__ hb, const float* __restrict__ s1, const float* __restrict__ s2,
    const float* __restrict__ gamma, const float* __restrict__ beta,
    unsigned short* __restrict__ hbnb)
{
  int base = (blockIdx.x*256 + threadIdx.x) * 2;
  int c0 = base & (DM - 1);
  ushort2 hv = *(const ushort2*)(hb + base);
  float mA = s1[c0] * (1.f/NN),   mB = s1[c0+1] * (1.f/NN);
  float vA = s2[c0] * (1.f/NN) - mA*mA, vB = s2[c0+1] * (1.f/NN) - mB*mB;
  float iA = rsqrtf(vA + 1e-5f), iB = rsqrtf(vB + 1e-5f);
  float a = (bf2f(hv.x) - mA)*iA*gamma[c0]   + beta[c0];
  float b = (bf2f(hv.y) - mB)*iB*gamma[c0+1] + beta[c0+1];
  ushort2 o; o.x = f2bf(a); o.y = f2bf(b);
  *(ushort2*)(hbnb + base) = o;
}

// ---------------- gemm3: [xm|z] = hbnb @ w_in^T (M=8192,K=256,N=1024), bf16 out ----------------
__global__ __launch_bounds__(256) void gemm3_kernel(
    const unsigned short* __restrict__ Ab, const unsigned short* __restrict__ Wb,
    unsigned short* __restrict__ xmb, unsigned short* __restrict__ zb)
{
  __shared__ uint4 alds[2048];  // 64 rows x 32 slots (swizzled), 32 KB
  const int t = threadIdx.x;
  const int wave = t >> 6, lane = t & 63, r = lane & 15, q = lane >> 4;
  const int mb = ((int)blockIdx.x & 127) * 64;
  const int nb = ((int)blockIdx.x >> 7) * 128;
  const int wm = wave & 1, wn = wave >> 1;

  #pragma unroll
  for (int j = 0; j < 8; ++j){
    int si = j*256 + t;
    int row = si >> 5, dg = si & 31;
    int sg = dg ^ (row & 31);
    ASYNC16(Ab + (size_t)(mb + row)*DM + sg*8, (char*)alds + si*16);
  }
  __syncthreads();

  f32x4 acc[2][4];
  #pragma unroll
  for (int mi = 0; mi < 2; ++mi)
    #pragma unroll
    for (int ni = 0; ni < 4; ++ni) acc[mi][ni] = zero4();

  const unsigned short* bp[4];
  #pragma unroll
  for (int ni = 0; ni < 4; ++ni)
    bp[ni] = Wb + (size_t)(nb + wn*64 + ni*16 + r)*DM + q*8;
  FragU fb[4];
  #pragma unroll
  for (int ni = 0; ni < 4; ++ni) fb[ni].u4 = *(const uint4*)bp[ni];

  #pragma unroll
  for (int it = 0; it < 8; ++it){
    FragU fbn[4];
    if (it < 7){
      #pragma unroll
      for (int ni = 0; ni < 4; ++ni) fbn[ni].u4 = *(const uint4*)(bp[ni] + (it+1)*32);
    }
    FragU fa[2];
    #pragma unroll
    for (int mi = 0; mi < 2; ++mi){
      int row = wm*32 + mi*16 + r;
      int g = it*4 + q;
      fa[mi].u4 = alds[row*32 + (g ^ (row & 31))];
    }
    #pragma unroll
    for (int mi = 0; mi < 2; ++mi)
      #pragma unroll
      for (int ni = 0; ni < 4; ++ni)
        acc[mi][ni] = __builtin_amdgcn_mfma_f32_16x16x32_bf16(fa[mi].v, fb[ni].v, acc[mi][ni], 0, 0, 0);
    if (it < 7){
      #pragma unroll
      for (int ni = 0; ni < 4; ++ni) fb[ni] = fbn[ni];
    }
  }
  #pragma unroll
  for (int mi = 0; mi < 2; ++mi)
    #pragma unroll
    for (int ni = 0; ni < 4; ++ni){
      int nc = nb + wn*64 + ni*16 + r;
      unsigned short* dst = (nc < 512) ? (xmb + nc) : (zb + (nc - 512));
      #pragma unroll
      for (int jr = 0; jr < 4; ++jr){
        int m = mb + wm*32 + mi*16 + q*4 + jr;
        dst[(size_t)m*DI] = f2bf(acc[mi][ni][jr]);
      }
    }
}

// ---------------- conv: depthwise causal D=4 + SiLU, bf16 out only ----------------
__global__ __launch_bounds__(256) void conv_kernel(
    const unsigned short* __restrict__ xmb, const float* __restrict__ conv_w, const float* __restrict__ conv_b,
    unsigned short* __restrict__ xcb)
{
  const int d0 = threadIdx.x * 2;
  const int n0 = blockIdx.x * 32;
  float4 wa = *(const float4*)(conv_w + (size_t)d0*4);
  float4 wb = *(const float4*)(conv_w + (size_t)d0*4 + 4);
  float2 bias = *(const float2*)(conv_b + d0);
  float x0a=0.f,x1a=0.f,x2a=0.f, x0b=0.f,x1b=0.f,x2b=0.f;
  #pragma unroll
  for (int j = 0; j < 3; ++j){
    int n = n0 - 3 + j;
    float va = 0.f, vb = 0.f;
    if (n >= 0){
      ushort2 u = *(const ushort2*)(xmb + (size_t)n*DI + d0);
      va = bf2f(u.x); vb = bf2f(u.y);
    }
    if (j == 0){ x0a = va; x0b = vb; }
    else if (j == 1){ x1a = va; x1b = vb; }
    else { x2a = va; x2b = vb; }
  }
  for (int j = 0; j < 32; ++j){
    int n = n0 + j;
    ushort2 u = *(const ushort2*)(xmb + (size_t)n*DI + d0);
    float x3a = bf2f(u.x), x3b = bf2f(u.y);
    float sa = bias.x + wa.x*x0a + wa.y*x1a + wa.z*x2a + wa.w*x3a;
    float sb = bias.y + wb.x*x0b + wb.y*x1b + wb.z*x2b + wb.w*x3b;
    float va = sa * sigmoidf_(sa);
    float vb = sb * sigmoidf_(sb);
    ushort2 o; o.x = f2bf(va); o.y = f2bf(vb);
    *(ushort2*)(xcb + (size_t)n*DI + d0) = o;
    x0a=x1a; x1a=x2a; x2a=x3a;
    x0b=x1b; x1b=x2b; x2b=x3b;
  }
}

// ---------------- gemm4: x_dbl = xc @ w_xproj^T (M=8192,K=512,N=48) ----------------
__global__ __launch_bounds__(256) void gemm4_kernel(
    const unsigned short* __restrict__ Ab, const unsigned short* __restrict__ Wb, float* __restrict__ xdbl)
{
  __shared__ uint4 alds[2048];  // 32 rows x 64 slots, 32 KB
  const int t = threadIdx.x;
  const int wave = t >> 6, lane = t & 63, r = lane & 15, q = lane >> 4;
  const int m0 = (int)blockIdx.x * 32;
  #pragma unroll
  for (int j = 0; j < 8; ++j){
    int si = j*256 + t;
    int row = si >> 6, dg = si & 63;
    int sg = dg ^ (row & 31);
    ASYNC16(Ab + (size_t)(m0 + row)*DI + sg*8, (char*)alds + si*16);
  }
  __syncthreads();
  f32x4 acc[2][3];
  #pragma unroll
  for (int mi = 0; mi < 2; ++mi)
    #pragma unroll
    for (int ni = 0; ni < 3; ++ni) acc[mi][ni] = zero4();
  const int kq = wave * 128;
  const unsigned short* bp[3];
  #pragma unroll
  for (int ni = 0; ni < 3; ++ni) bp[ni] = Wb + (size_t)(ni*16 + r)*DI + kq + q*8;
  FragU fb[3];
  #pragma unroll
  for (int ni = 0; ni < 3; ++ni) fb[ni].u4 = *(const uint4*)bp[ni];
  #pragma unroll
  for (int it = 0; it < 4; ++it){
    FragU fbn[3];
    if (it < 3){
      #pragma unroll
      for (int ni = 0; ni < 3; ++ni) fbn[ni].u4 = *(const uint4*)(bp[ni] + (it+1)*32);
    }
    FragU fa[2];
    #pragma unroll
    for (int mi = 0; mi < 2; ++mi){
      int row = mi*16 + r;
      int g = (kq >> 3) + it*4 + q;
      fa[mi].u4 = alds[row*64 + (g ^ (row & 31))];
    }
    #pragma unroll
    for (int mi = 0; mi < 2; ++mi)
      #pragma unroll
      for (int ni = 0; ni < 3; ++ni)
        acc[mi][ni] = __builtin_amdgcn_mfma_f32_16x16x32_bf16(fa[mi].v, fb[ni].v, acc[mi][ni], 0, 0, 0);
    if (it < 3){
      #pragma unroll
      for (int ni = 0; ni < 3; ++ni) fb[ni] = fbn[ni];
    }
  }
  __syncthreads();
  float* red = (float*)alds;
  if (wave > 0){
    int base = ((wave - 1)*64 + lane)*24;
    #pragma unroll
    for (int mi = 0; mi < 2; ++mi)
      #pragma unroll
      for (int ni = 0; ni < 3; ++ni)
        #pragma unroll
        for (int jr = 0; jr < 4; ++jr)
          red[base + (mi*3 + ni)*4 + jr] = acc[mi][ni][jr];
  }
  __syncthreads();
  if (wave == 0){
    #pragma unroll
    for (int w = 0; w < 3; ++w){
      int base = (w*64 + lane)*24;
      #pragma unroll
      for (int mi = 0; mi < 2; ++mi)
        #pragma unroll
        for (int ni = 0; ni < 3; ++ni)
          #pragma unroll
          for (int jr = 0; jr < 4; ++jr)
            acc[mi][ni][jr] += red[base + (mi*3 + ni)*4 + jr];
    }
    #pragma unroll
    for (int mi = 0; mi < 2; ++mi)
      #pragma unroll
      for (int ni = 0; ni < 3; ++ni)
        #pragma unroll
        for (int jr = 0; jr < 4; ++jr)
          xdbl[(size_t)(m0 + mi*16 + q*4 + jr)*48 + ni*16 + r] = acc[ni >= 0 ? mi : mi][ni][jr];
  }
}

// ---------------- dt = softplus(dt_r @ w_dt^T + b_dt), 64-row strips ----------------
__global__ __launch_bounds__(256) void dt_kernel(
    const float* __restrict__ xdbl, const float* __restrict__ w_dt, const float* __restrict__ b_dt,
    float* __restrict__ dt)
{
  __shared__ float xr[64*16];
  const int t = threadIdx.x;
  const int dg = (int)blockIdx.x & 1;
  const int n0 = ((int)blockIdx.x >> 1) * 64;
  const int d = dg*256 + t;
  #pragma unroll
  for (int j = 0; j < 4; ++j){
    int idx = t + 256*j;
    xr[idx] = xdbl[(size_t)(n0 + (idx >> 4))*48 + (idx & 15)];
  }
  __syncthreads();
  const float4* wp = (const float4*)(w_dt + (size_t)d*16);
  float4 w0 = wp[0], w1 = wp[1], w2 = wp[2], w3 = wp[3];
  float bias = b_dt[d];
  for (int j = 0; j < 64; ++j){
    const float4* xp = (const float4*)(xr + j*16);
    float4 a0 = xp[0], a1 = xp[1], a2 = xp[2], a3 = xp[3];
    float a = bias;
    a += w0.x*a0.x + w0.y*a0.y + w0.z*a0.z + w0.w*a0.w;
    a += w1.x*a1.x + w1.y*a1.y + w1.z*a1.z + w1.w*a1.w;
    a += w2.x*a2.x + w2.y*a2.y + w2.z*a2.z + w2.w*a2.w;
    a += w3.x*a3.x + w3.y*a3.y + w3.z*a3.z + w3.w*a3.w;
    float o = (a > 20.f) ? a : log1pf(__expf(a));
    dt[(size_t)(n0 + j)*DI + d] = o;
  }
}

// ---------------- scanA: per-chunk local recurrence -> interleaved {P,F} ----------------
__global__ __launch_bounds__(256) void scanA_kernel(
    const float* __restrict__ dt, const unsigned short* __restrict__ xcb,
    const float* __restrict__ xdbl, const float* __restrict__ A_log,
    float2* __restrict__ PF)
{
  __shared__ float Bs[CL*DST];
  const int t = threadIdx.x;
  const int c = (int)blockIdx.x >> 1;
  const int d = (((int)blockIdx.x & 1) << 8) + t;
  #pragma unroll
  for (int j = 0; j < 2; ++j){
    int idx = t + 256*j;
    Bs[idx] = xdbl[(size_t)(c*CL + (idx >> 4))*48 + 16 + (idx & 15)];
  }
  __syncthreads();
  float Av[DST], hs[DST];
  {
    const float4* Ap = (const float4*)(A_log + (size_t)d*DST);
    #pragma unroll
    for (int s4 = 0; s4 < 4; ++s4){
      float4 a4 = Ap[s4];
      Av[s4*4+0] = -__expf(a4.x); Av[s4*4+1] = -__expf(a4.y);
      Av[s4*4+2] = -__expf(a4.z); Av[s4*4+3] = -__expf(a4.w);
    }
  }
  #pragma unroll
  for (int s = 0; s < DST; ++s) hs[s] = 0.f;
  float sdt = 0.f;
  const size_t rb = (size_t)c*CL*DI + d;
  float dtv = dt[rb], xcv = bf2f(xcb[rb]);
  for (int tt = 0; tt < CL; ++tt){
    float dtn = 0.f, xcn = 0.f;
    if (tt + 1 < CL){
      dtn = dt[rb + (size_t)(tt+1)*DI];
      xcn = bf2f(xcb[rb + (size_t)(tt+1)*DI]);
    }
    float u = dtv * xcv;
    sdt += dtv;
    float bv[DST];
    *(float4*)&bv[0]  = *(const float4*)&Bs[tt*16];
    *(float4*)&bv[4]  = *(const float4*)&Bs[tt*16 + 4];
    *(float4*)&bv[8]  = *(const float4*)&Bs[tt*16 + 8];
    *(float4*)&bv[12] = *(const float4*)&Bs[tt*16 + 12];
    #pragma unroll
    for (int s = 0; s < DST; ++s)
      hs[s] = __expf(dtv * Av[s]) * hs[s] + u * bv[s];
    dtv = dtn; xcv = xcn;
  }
  float4* out = (float4*)(PF + (size_t)c*(DI*DST) + (size_t)d*DST);
  #pragma unroll
  for (int j = 0; j < 8; ++j){
    float4 v;
    v.x = __expf(Av[2*j] * sdt);   v.y = hs[2*j];
    v.z = __expf(Av[2*j+1] * sdt); v.w = hs[2*j+1];
    out[j] = v;
  }
}

// ---------------- scanB: sequential carry across 256 chunks, batched prefetch ----------------
__global__ __launch_bounds__(128) void scanB_kernel(
    const float2* __restrict__ PF, float* __restrict__ Cy)
{
  const int ds = (int)blockIdx.x*128 + (int)threadIdx.x;
  float2 A0[16], A1[16];
  #pragma unroll
  for (int j = 0; j < 16; ++j) A0[j] = PF[(size_t)j*8192 + ds];
  #pragma unroll
  for (int j = 0; j < 16; ++j) A1[j] = PF[(size_t)(16 + j)*8192 + ds];
  float cy = 0.f;
  Cy[ds] = 0.f;
  #pragma unroll
  for (int g = 0; g < 16; ++g){
    #pragma unroll
    for (int j = 0; j < 16; ++j){
      int i = g*16 + j;
      if (i < NC - 1){
        float2 pf = (g & 1) ? A1[j] : A0[j];
        cy = pf.x * cy + pf.y;
        Cy[(size_t)(i + 1)*8192 + ds] = cy;
      }
    }
    int gn = g + 2;
    if (gn < 16){
      #pragma unroll
      for (int j = 0; j < 16; ++j){
        float2 v = PF[(size_t)(gn*16 + j)*8192 + ds];
        if (g & 1) A1[j] = v; else A0[j] = v;
      }
    }
  }
}

// ---------------- scanC: recompute with carry, emit gated y (bf16) ----------------
__global__ __launch_bounds__(256) void scanC_kernel(
    const float* __restrict__ dt, const unsigned short* __restrict__ xcb,
    const float* __restrict__ xdbl, const float* __restrict__ A_log,
    const float* __restrict__ Cy, const float* __restrict__ Dskip,
    const unsigned short* __restrict__ zb, unsigned short* __restrict__ yb)
{
  __shared__ float Bs[CL*DST];
  __shared__ float Cs[CL*DST];
  const int t = threadIdx.x;
  const int c = (int)blockIdx.x >> 1;
  const int d = (((int)blockIdx.x & 1) << 8) + t;
  #pragma unroll
  for (int j = 0; j < 2; ++j){
    int idx = t + 256*j;
    int tg = c*CL + (idx >> 4);
    Bs[idx] = xdbl[(size_t)tg*48 + 16 + (idx & 15)];
    Cs[idx] = xdbl[(size_t)tg*48 + 32 + (idx & 15)];
  }
  __syncthreads();
  float Av[DST], hs[DST];
  {
    const float4* Ap = (const float4*)(A_log + (size_t)d*DST);
    #pragma unroll
    for (int s4 = 0; s4 < 4; ++s4){
      float4 a4 = Ap[s4];
      Av[s4*4+0] = -__expf(a4.x); Av[s4*4+1] = -__expf(a4.y);
      Av[s4*4+2] = -__expf(a4.z); Av[s4*4+3] = -__expf(a4.w);
    }
  }
  {
    const float4* hp4 = (const float4*)(Cy + (size_t)c*(DI*DST) + (size_t)d*DST);
    #pragma unroll
    for (int s4 = 0; s4 < 4; ++s4){
      float4 h4 = hp4[s4];
      hs[s4*4+0] = h4.x; hs[s4*4+1] = h4.y; hs[s4*4+2] = h4.z; hs[s4*4+3] = h4.w;
    }
  }
  const float Dv = Dskip[d];
  const size_t rb = (size_t)c*CL*DI + d;
  float dtv = dt[rb], xcv = bf2f(xcb[rb]);
  unsigned short zv0 = zb[rb];
  for (int tt = 0; tt < CL; ++tt){
    float dtn = 0.f, xcn = 0.f;
    unsigned short zn = 0;
    if (tt + 1 < CL){
      dtn = dt[rb + (size_t)(tt+1)*DI];
      xcn = bf2f(xcb[rb + (size_t)(tt+1)*DI]);
      zn  = zb[rb + (size_t)(tt+1)*DI];
    }
    float u = dtv * xcv;
    float bv[DST], cv[DST];
    *(float4*)&bv[0]  = *(const float4*)&Bs[tt*16];
    *(float4*)&bv[4]  = *(const float4*)&Bs[tt*16 + 4];
    *(float4*)&bv[8]  = *(const float4*)&Bs[tt*16 + 8];
    *(float4*)&bv[12] = *(const float4*)&Bs[tt*16 + 12];
    *(float4*)&cv[0]  = *(const float4*)&Cs[tt*16];
    *(float4*)&cv[4]  = *(const float4*)&Cs[tt*16 + 4];
    *(float4*)&cv[8]  = *(const float4*)&Cs[tt*16 + 8];
    *(float4*)&cv[12] = *(const float4*)&Cs[tt*16 + 12];
    float y0 = 0.f, y1 = 0.f;
    #pragma unroll
    for (int s = 0; s < DST; s += 2){
      hs[s]   = __expf(dtv * Av[s])   * hs[s]   + u * bv[s];
      hs[s+1] = __expf(dtv * Av[s+1]) * hs[s+1] + u * bv[s+1];
      y0 += hs[s]   * cv[s];
      y1 += hs[s+1] * cv[s+1];
    }
    float z = bf2f(zv0);
    float yf = ((y0 + y1) + Dv * xcv) * (z * sigmoidf_(z));
    yb[rb + (size_t)tt*DI] = f2bf(yf);
    dtv = dtn; xcv = xcn; zv0 = zn;
  }
}

// ---------------- gemm5: out = y @ w_out^T + hbn (M=8192,K=512,N=256) ----------------
__global__ __launch_bounds__(512) void gemm5_kernel(
    const unsigned short* __restrict__ yb, const unsigned short* __restrict__ Wb,
    const unsigned short* __restrict__ hbnb, float* __restrict__ out)
{
  __shared__ uint4 alds[2048];  // 32 rows x 64 slots, 32 KB
  const int t = threadIdx.x;
  const int wave = t >> 6, lane = t & 63, r = lane & 15, q = lane >> 4;
  const int m0 = (int)blockIdx.x * 32;
  #pragma unroll
  for (int j = 0; j < 4; ++j){
    int si = j*512 + t;
    int row = si >> 6, dg = si & 63;
    int sg = dg ^ (row & 31);
    ASYNC16(yb + (size_t)(m0 + row)*DI + sg*8, (char*)alds + si*16);
  }
  __syncthreads();
  f32x4 acc[2][2];
  #pragma unroll
  for (int mi = 0; mi < 2; ++mi)
    #pragma unroll
    for (int ni = 0; ni < 2; ++ni) acc[mi][ni] = zero4();
  const int nw = wave * 32;
  const unsigned short* bp0 = Wb + (size_t)(nw + r)*DI + q*8;
  const unsigned short* bp1 = Wb + (size_t)(nw + 16 + r)*DI + q*8;
  FragU fb0, fb1;
  fb0.u4 = *(const uint4*)bp0;
  fb1.u4 = *(const uint4*)bp1;
  #pragma unroll
  for (int it = 0; it < 16; ++it){
    FragU fn0, fn1;
    if (it < 15){
      fn0.u4 = *(const uint4*)(bp0 + (it+1)*32);
      fn1.u4 = *(const uint4*)(bp1 + (it+1)*32);
    }
    FragU fa[2];
    #pragma unroll
    for (int mi = 0; mi < 2; ++mi){
      int row = mi*16 + r;
      int g = it*4 + q;
      fa[mi].u4 = alds[row*64 + (g ^ (row & 31))];
    }
    acc[0][0] = __builtin_amdgcn_mfma_f32_16x16x32_bf16(fa[0].v, fb0.v, acc[0][0], 0, 0, 0);
    acc[0][1] = __builtin_amdgcn_mfma_f32_16x16x32_bf16(fa[0].v, fb1.v, acc[0][1], 0, 0, 0);
    acc[1][0] = __builtin_amdgcn_mfma_f32_16x16x32_bf16(fa[1].v, fb0.v, acc[1][0], 0, 0, 0);
    acc[1][1] = __builtin_amdgcn_mfma_f32_16x16x32_bf16(fa[1].v, fb1.v, acc[1][1], 0, 0, 0);
    if (it < 15){ fb0 = fn0; fb1 = fn1; }
  }
  #pragma unroll
  for (int mi = 0; mi < 2; ++mi)
    #pragma unroll
    for (int ni = 0; ni < 2; ++ni){
      const int n = nw + ni*16 + r;
      #pragma unroll
      for (int jr = 0; jr < 4; ++jr){
        const int m = m0 + mi*16 + q*4 + jr;
        size_t idx = (size_t)m*DM + n;
        out[idx] = acc[mi][ni][jr] + bf2f(hbnb[idx]);
      }
    }
}

// ---------------- launch ----------------
extern "C" void kernel_launch(void* const* d_in, const int* in_sizes, int n_in,
                              void* d_out, int out_size, void* d_ws, size_t ws_size,
                              hipStream_t stream)
{
  const float* x      = (const float*)d_in[0];
  const float* adj    = (const float*)d_in[1];
  const float* w_gcn  = (const float*)d_in[2];
  const float* b_gcn  = (const float*)d_in[3];
  const float* gamma  = (const float*)d_in[4];
  const float* beta   = (const float*)d_in[5];
  const float* w_in   = (const float*)d_in[6];
  const float* conv_w = (const float*)d_in[7];
  const float* conv_b = (const float*)d_in[8];
  const float* w_xp   = (const float*)d_in[9];
  const float* w_dt   = (const float*)d_in[10];
  const float* b_dt   = (const float*)d_in[11];
  const float* A_log  = (const float*)d_in[12];
  const float* D_skip = (const float*)d_in[13];
  const float* w_out  = (const float*)d_in[14];
  float* out = (float*)d_out;
  char* ws = (char*)d_ws;
  if (ws_size < WS_NEED) return;

  unsigned short* xwT   = (unsigned short*)(ws + OFF_XWT);
  float*          hp    = (float*)(ws + OFF_HP);
  unsigned short* hb    = (unsigned short*)(ws + OFF_HB);
  unsigned short* hbnb  = (unsigned short*)(ws + OFF_HBNB);
  unsigned short* winb  = (unsigned short*)(ws + OFF_WINB);
  unsigned short* wxpb  = (unsigned short*)(ws + OFF_WXPB);
  unsigned short* woutb = (unsigned short*)(ws + OFF_WOUTB);
  unsigned short* xmb   = (unsigned short*)(ws + OFF_XMB);
  unsigned short* zb    = (unsigned short*)(ws + OFF_ZB);
  unsigned short* xcb   = (unsigned short*)(ws + OFF_XCB);
  float*          xdbl  = (float*)(ws + OFF_XDBL);
  float*          dtb   = (float*)(ws + OFF_DT);
  float2*         PF    = (float2*)(ws + OFF_PF);
  float*          Cy    = (float*)(ws + OFF_CY);
  unsigned short* yb    = (unsigned short*)(ws + OFF_YB);
  float*          bns   = (float*)(ws + OFF_BNS);
  float*          bns2  = (float*)(ws + OFF_BNS2);

  hipMemsetAsync(bns, 0, 2*256*sizeof(float), stream);

  // 80KB dynamic LDS for gemm2 (2 blocks/CU x 80KB = 160KB/CU)
  hipFuncSetAttribute((const void*)gemm2_kernel,
                      hipFuncAttributeMaxDynamicSharedMemorySize, 81920);

  prep_kernel   <<<1024, 256, 0, stream>>>(w_in, w_xp, w_out, winb, wxpb, woutb);
  gemm1_kernel  <<<512,  256, 0, stream>>>(x, w_gcn, xwT);
  gemm2_kernel  <<<1024, 256, 81920, stream>>>(adj, xwT, hp);
  hred_kernel   <<<256,  256, 0, stream>>>(hp, b_gcn, hb, bns, bns2);
  bnapply_kernel<<<4096, 256, 0, stream>>>(hb, bns, bns2, gamma, beta, hbnb);
  gemm3_kernel  <<<1024, 256, 0, stream>>>(hbnb, winb, xmb, zb);
  conv_kernel   <<<256,  256, 0, stream>>>(xmb, conv_w, conv_b, xcb);
  gemm4_kernel  <<<256,  256, 0, stream>>>(xcb, wxpb, xdbl);
  dt_kernel     <<<256,  256, 0, stream>>>(xdbl, w_dt, b_dt, dtb);
  scanA_kernel  <<<512,  256, 0, stream>>>(dtb, xcb, xdbl, A_log, PF);
  scanB_kernel  <<<64,   128, 0, stream>>>(PF, Cy);
  scanC_kernel  <<<512,  256, 0, stream>>>(dtb, xcb, xdbl, A_log, Cy, D_skip, zb, yb);
  gemm5_kernel  <<<256,  512, 0, stream>>>(yb, woutb, hbnb, out);
}